// Round 7
// baseline (362.090 us; speedup 1.0000x reference)
//
#include <hip/hip_runtime.h>
#include <math.h>

// SSIM loss on 8x8 blockified images (16,3,512,512) fp32.
// Reflect-pad + 11x11 separable Gaussian on an 8x8 block == M = W * S * W^T,
// W = reflect-folded 8x8 Gaussian fold matrix. 5 stats (x,y,x2,y2,xy) per
// block-channel; 8 lanes per block-channel, lane owns one ROW (2x float4).
// v2: barrier-free. The mid-sandwich transpose is a 3-stage ds_swizzle
// butterfly within each 8-lane group (register-to-register, compiler-visible
// deps — no LDS ordering hazards, no __syncthreads in the stat phase).
// 5 stat chains are independent -> full ILP, occupancy VGPR-limited only.
// Reduction: 64-lane shuffle butterfly -> 4 partials in 16B LDS -> one
// fixed-point (2^30) int64 atomicAdd into one of 16 slots; last block
// (device-scope done-counter) sums slots and writes 1 - mean.
// Launch: hipMemsetAsync zeroes slots+counter, then ONE kernel (2 graph nodes).

#define NBC      196608      // 16*3*64*64 block-channels
#define NPIX     12582912.0  // total ssim_map elements
#define GRID1    6144        // NBC / 32 groups per 256-thread block
#define NSLOT    16
#define FIXSCALE 1073741824.0f // 2^30
#define C1       1.0e-4f
#define C2       9.0e-4f

struct WMat { float w[64]; };

template<int OFF>
__device__ __forceinline__ float swzf(float v) {
    return __int_as_float(__builtin_amdgcn_ds_swizzle(__float_as_int(v), OFF));
}

// One butterfly exchange: regs (p,q=p^m) across lanes l and l^m.
// b = lane's bit for this stage. Verified: lane with b=0 sends A[q], receives
// partner's A[p] into A[q]; lane with b=1 sends A[p], receives into A[p].
#define BPAIR(p, q, OFFC) do {                  \
        float t = b ? A[p] : A[q];              \
        float r = swzf<OFFC>(t);                \
        A[p] = b ? r : A[p];                    \
        A[q] = b ? A[q] : r;                    \
    } while (0)

__device__ __forceinline__ void transpose8(float A[8], int l) {
    { const bool b = (l & 1) != 0;   // stage m=1: xor mask 1 -> 0x041F
      BPAIR(0,1,0x041F); BPAIR(2,3,0x041F); BPAIR(4,5,0x041F); BPAIR(6,7,0x041F); }
    { const bool b = (l & 2) != 0;   // stage m=2
      BPAIR(0,2,0x081F); BPAIR(1,3,0x081F); BPAIR(4,6,0x081F); BPAIR(5,7,0x081F); }
    { const bool b = (l & 4) != 0;   // stage m=4
      BPAIR(0,4,0x101F); BPAIR(1,5,0x101F); BPAIR(2,6,0x101F); BPAIR(3,7,0x101F); }
}

__device__ __forceinline__ void matvec8(const float* __restrict__ w,
                                        const float S[8], float O[8]) {
#pragma unroll
    for (int i = 0; i < 8; i++) {
        float a = w[i * 8 + 0] * S[0];
#pragma unroll
        for (int c = 1; c < 8; c++) a = fmaf(w[i * 8 + c], S[c], a);
        O[i] = a;
    }
}

// out = column l of W*S*W^T (same permutation for every stat -> aligned)
__device__ __forceinline__ void sandwich(const float* __restrict__ w,
                                         const float S[8], float out_v[8], int l) {
    float A[8];
    matvec8(w, S, A);        // lane l: row l of S*W^T
    transpose8(A, l);        // lane l: column l of S*W^T
    matvec8(w, A, out_v);    // lane l: column l of W*S*W^T
}

__global__ __launch_bounds__(256, 4) void ssim_fused(const float* __restrict__ x,
                                                     const float* __restrict__ y,
                                                     unsigned long long* __restrict__ slots,
                                                     unsigned* __restrict__ counter,
                                                     float* __restrict__ out,
                                                     WMat Wm) {
    __shared__ float redbuf[4];

    const int tid = threadIdx.x;
    const int l   = tid & 7;                 // owned row of the 8x8 block
    const int grp = tid >> 3;                // group in block [0,32)
    const int bc  = blockIdx.x * 32 + grp;   // block-channel [0, NBC)

    const int wb  = bc & 63;
    const int hb  = (bc >> 6) & 63;
    const int img = bc >> 12;                // b*3 + c in [0,48)

    const int rowbase = (img * 512 + hb * 8 + l) * 512 + wb * 8;

    const float4 x0 = *reinterpret_cast<const float4*>(x + rowbase);
    const float4 x1 = *reinterpret_cast<const float4*>(x + rowbase + 4);
    const float4 y0 = *reinterpret_cast<const float4*>(y + rowbase);
    const float4 y1 = *reinterpret_cast<const float4*>(y + rowbase + 4);

    float X[8] = {x0.x, x0.y, x0.z, x0.w, x1.x, x1.y, x1.z, x1.w};
    float Y[8] = {y0.x, y0.y, y0.z, y0.w, y1.x, y1.y, y1.z, y1.w};

    const float* w = Wm.w;

    float mx[8], my[8], mxx[8], myy[8], mxy[8], T[8];
    sandwich(w, X, mx, l);
    sandwich(w, Y, my, l);
#pragma unroll
    for (int i = 0; i < 8; i++) T[i] = X[i] * X[i];
    sandwich(w, T, mxx, l);
#pragma unroll
    for (int i = 0; i < 8; i++) T[i] = Y[i] * Y[i];
    sandwich(w, T, myy, l);
#pragma unroll
    for (int i = 0; i < 8; i++) T[i] = X[i] * Y[i];
    sandwich(w, T, mxy, l);

    float s = 0.f;
#pragma unroll
    for (int p = 0; p < 8; p++) {
        float a = mx[p], b = my[p];
        float sx  = mxx[p] - a * a;
        float sy  = myy[p] - b * b;
        float sxy = mxy[p] - a * b;
        float num = fmaf(2.f, a * b, C1) * fmaf(2.f, sxy, C2);
        float den = (fmaf(a, a, b * b) + C1) * (sx + sy + C2);
        float r = __builtin_amdgcn_rcpf(den);
        r = r * (2.f - den * r);               // Newton -> full fp32
        s = fmaf(num, r, s);
    }

    // 64-lane butterfly, 4 wave partials via 16B LDS, one atomic per block
#pragma unroll
    for (int off = 32; off > 0; off >>= 1) s += __shfl_xor(s, off, 64);
    if ((tid & 63) == 0) redbuf[tid >> 6] = s;
    __syncthreads();
    if (tid == 0) {
        float bs = (redbuf[0] + redbuf[1]) + (redbuf[2] + redbuf[3]);
        long long fx = llrintf(bs * FIXSCALE);
        atomicAdd(&slots[blockIdx.x & (NSLOT - 1)], (unsigned long long)fx);
        __threadfence();
        unsigned old = atomicAdd(counter, 1u);
        if (old == (unsigned)(GRID1 - 1)) {
            __threadfence();
            long long tot = 0;
#pragma unroll
            for (int i = 0; i < NSLOT; i++)
                tot += (long long)atomicAdd(&slots[i], 0ull);   // coherent read
            out[0] = (float)(1.0 - ((double)tot / (double)FIXSCALE) / NPIX);
        }
    }
}

static WMat make_w() {
    double g[11]; double s = 0.0;
    for (int k = 0; k < 11; k++) { double d = k - 5.0; g[k] = exp(-d * d / 4.5); s += g[k]; }
    for (int k = 0; k < 11; k++) g[k] /= s;
    WMat W{};
    for (int j = 0; j < 8; j++)
        for (int k = 0; k < 11; k++) {
            int t = j + k - 5;
            int rr = t < 0 ? -t : (t > 7 ? 14 - t : t);
            W.w[j * 8 + rr] += (float)g[k];
        }
    return W;
}

extern "C" void kernel_launch(void* const* d_in, const int* in_sizes, int n_in,
                              void* d_out, int out_size, void* d_ws, size_t ws_size,
                              hipStream_t stream) {
    const float* x = (const float*)d_in[0];
    const float* y = (const float*)d_in[1];
    unsigned long long* slots = (unsigned long long*)d_ws;           // 16 x u64
    unsigned* counter = (unsigned*)((char*)d_ws + NSLOT * 8);        // u32
    WMat W = make_w();
    hipMemsetAsync(d_ws, 0, NSLOT * 8 + 4, stream);                  // capture-safe
    ssim_fused<<<GRID1, 256, 0, stream>>>(x, y, slots, counter, (float*)d_out, W);
}

// Round 8
// 160.525 us; speedup vs baseline: 2.2557x; 2.2557x over previous
//
#include <hip/hip_runtime.h>
#include <math.h>

// SSIM loss on 8x8 blockified images (16,3,512,512) fp32.
// v3: ONE THREAD PER BLOCK-CHANNEL. X,Y (8x8 each) live fully in VGPRs;
// reflect-pad + 11x11 separable Gaussian == M_t = W * S_t * W^T with the
// fixed fold matrix W, evaluated column-by-column:
//   per output col j:  u_t = S_t * w_j  (row-wise dots, shares xw=X*w term)
//   per output row i:  m_t = w_i . u_t  -> SSIM epilogue, accumulate.
// No cross-lane ops, no LDS, no barriers in the compute (lesson from v2:
// ds_swizzle is a DS-pipe op, NOT register-to-register — it serialized us).
// j-loop kept rolled (code ~4KB, I-cache resident); i,c,k loops unrolled.
// Reduction: 64-lane shuffle -> 4 wave partials in LDS -> fixed-point 2^30
// int64 atomicAdd into 16 slots; last block (device counter) writes 1-mean.

#define NBC      196608      // 16*3*64*64 block-channels
#define NPIX     12582912.0  // total ssim_map elements
#define GRID     768         // NBC / 256 threads
#define NSLOT    16
#define FIXSCALE 1073741824.0f // 2^30
#define C1       1.0e-4f
#define C2       9.0e-4f

struct WMat { float w[64]; };

__global__ __launch_bounds__(256, 2) void ssim_fused(
    const float* __restrict__ x, const float* __restrict__ y,
    unsigned long long* __restrict__ slots, unsigned* __restrict__ counter,
    float* __restrict__ out, WMat Wm)
{
    __shared__ float redbuf[4];

    const int tid = threadIdx.x;
    const int bc  = blockIdx.x * 256 + tid;   // block-channel [0, NBC)
    const int wb  = bc & 63;                  // = lane -> coalesced columns
    const int hb  = (bc >> 6) & 63;
    const int img = bc >> 12;                 // b*3 + c in [0,48)
    const int base = (img * 512 + hb * 8) * 512 + wb * 8;

    float X[8][8], Y[8][8];
#pragma unroll
    for (int i = 0; i < 8; i++) {
        const float4 a0 = *reinterpret_cast<const float4*>(x + base + i * 512);
        const float4 a1 = *reinterpret_cast<const float4*>(x + base + i * 512 + 4);
        X[i][0]=a0.x; X[i][1]=a0.y; X[i][2]=a0.z; X[i][3]=a0.w;
        X[i][4]=a1.x; X[i][5]=a1.y; X[i][6]=a1.z; X[i][7]=a1.w;
        const float4 b0 = *reinterpret_cast<const float4*>(y + base + i * 512);
        const float4 b1 = *reinterpret_cast<const float4*>(y + base + i * 512 + 4);
        Y[i][0]=b0.x; Y[i][1]=b0.y; Y[i][2]=b0.z; Y[i][3]=b0.w;
        Y[i][4]=b1.x; Y[i][5]=b1.y; Y[i][6]=b1.z; Y[i][7]=b1.w;
    }

    float acc = 0.f;
#pragma unroll 1                     // keep code small; only w depends on j
    for (int j = 0; j < 8; j++) {
        float wj[8];
#pragma unroll
        for (int c = 0; c < 8; c++) wj[c] = Wm.w[j * 8 + c];   // uniform s_loads

        float ux[8], uy[8], uxx[8], uyy[8], uxy[8];
#pragma unroll
        for (int i = 0; i < 8; i++) {
            float sx = 0.f, sy = 0.f, sxx = 0.f, syy = 0.f, sxy = 0.f;
#pragma unroll
            for (int c = 0; c < 8; c++) {
                const float xv = X[i][c], yv = Y[i][c];
                const float xw = xv * wj[c];
                const float yw = yv * wj[c];
                sx += xw;  sy += yw;
                sxx = fmaf(xw, xv, sxx);
                syy = fmaf(yw, yv, syy);
                sxy = fmaf(xw, yv, sxy);
            }
            ux[i] = sx; uy[i] = sy; uxx[i] = sxx; uyy[i] = syy; uxy[i] = sxy;
        }

#pragma unroll
        for (int i = 0; i < 8; i++) {
            float mx = 0.f, my = 0.f, mxx = 0.f, myy = 0.f, mxy = 0.f;
#pragma unroll
            for (int k = 0; k < 8; k++) {
                const float wv = Wm.w[i * 8 + k];   // compile-time index
                mx  = fmaf(wv, ux[k],  mx);
                my  = fmaf(wv, uy[k],  my);
                mxx = fmaf(wv, uxx[k], mxx);
                myy = fmaf(wv, uyy[k], myy);
                mxy = fmaf(wv, uxy[k], mxy);
            }
            const float sigx  = mxx - mx * mx;
            const float sigy  = myy - my * my;
            const float sigxy = mxy - mx * my;
            const float num = fmaf(2.f, mx * my, C1) * fmaf(2.f, sigxy, C2);
            const float den = (fmaf(mx, mx, my * my) + C1) * (sigx + sigy + C2);
            float r = __builtin_amdgcn_rcpf(den);
            r = r * (2.f - den * r);               // Newton -> full fp32
            acc = fmaf(num, r, acc);
        }
    }

    // 64-lane butterfly, 4 wave partials via LDS, one atomic per block
#pragma unroll
    for (int off = 32; off > 0; off >>= 1) acc += __shfl_xor(acc, off, 64);
    if ((tid & 63) == 0) redbuf[tid >> 6] = acc;
    __syncthreads();
    if (tid == 0) {
        const float bs = (redbuf[0] + redbuf[1]) + (redbuf[2] + redbuf[3]);
        const long long fx = llrintf(bs * FIXSCALE);
        atomicAdd(&slots[blockIdx.x & (NSLOT - 1)], (unsigned long long)fx);
        __threadfence();
        const unsigned old = atomicAdd(counter, 1u);
        if (old == (unsigned)(GRID - 1)) {
            __threadfence();
            long long tot = 0;
#pragma unroll
            for (int i = 0; i < NSLOT; i++)
                tot += (long long)atomicAdd(&slots[i], 0ull);   // coherent read
            out[0] = (float)(1.0 - ((double)tot / (double)FIXSCALE) / NPIX);
        }
    }
}

static WMat make_w() {
    double g[11]; double s = 0.0;
    for (int k = 0; k < 11; k++) { double d = k - 5.0; g[k] = exp(-d * d / 4.5); s += g[k]; }
    for (int k = 0; k < 11; k++) g[k] /= s;
    WMat W{};
    for (int j = 0; j < 8; j++)
        for (int k = 0; k < 11; k++) {
            int t = j + k - 5;
            int rr = t < 0 ? -t : (t > 7 ? 14 - t : t);
            W.w[j * 8 + rr] += (float)g[k];
        }
    return W;
}

extern "C" void kernel_launch(void* const* d_in, const int* in_sizes, int n_in,
                              void* d_out, int out_size, void* d_ws, size_t ws_size,
                              hipStream_t stream) {
    const float* x = (const float*)d_in[0];
    const float* y = (const float*)d_in[1];
    unsigned long long* slots = (unsigned long long*)d_ws;        // 16 x u64
    unsigned* counter = (unsigned*)((char*)d_ws + NSLOT * 8);     // u32
    WMat W = make_w();
    hipMemsetAsync(d_ws, 0, NSLOT * 8 + 4, stream);               // capture-safe
    ssim_fused<<<GRID, 256, 0, stream>>>(x, y, slots, counter, (float*)d_out, W);
}

// Round 9
// 159.353 us; speedup vs baseline: 2.2722x; 1.0074x over previous
//
#include <hip/hip_runtime.h>
#include <math.h>

// SSIM loss on 8x8 blockified images (16,3,512,512) fp32.
// v4 = v3 (one thread per block-channel, all-VGPR, no cross-lane/LDS/barriers)
//      + amdgpu_waves_per_eu(2,2).
// v3 post-mortem: compiler targeted the 128-VGPR occupancy tier and spilled
// exactly 16 regs/thread (WRITE_SIZE 12.3MB = 64B x 196608 threads, FETCH +12MB
// reload). Live set is ~190 regs (X 64 + Y 64 + 40 stat temps + epilogue).
// Forcing waves_per_eu=(2,2) sets the allocator budget to 256 VGPRs -> no
// spill, at the cost of a 1.5-round grid tail (768 blocks / 512 resident).
// Math: reflect-pad + 11x11 separable Gaussian on an 8x8 block == W*S*W^T
// with the fixed fold matrix W; evaluated per output col j (u = S*w_j row
// dots sharing the xw term), then per output row i (w_i . u) -> SSIM epilogue.
// Reduction: 64-lane shuffle -> 4 wave partials in LDS -> fixed-point 2^30
// int64 atomicAdd into 16 slots; last block (device counter) writes 1-mean.

#define NBC      196608      // 16*3*64*64 block-channels
#define NPIX     12582912.0  // total ssim_map elements
#define GRID     768         // NBC / 256 threads
#define NSLOT    16
#define FIXSCALE 1073741824.0f // 2^30
#define C1       1.0e-4f
#define C2       9.0e-4f

struct WMat { float w[64]; };

__global__ __launch_bounds__(256)
__attribute__((amdgpu_waves_per_eu(2, 2)))
void ssim_fused(
    const float* __restrict__ x, const float* __restrict__ y,
    unsigned long long* __restrict__ slots, unsigned* __restrict__ counter,
    float* __restrict__ out, WMat Wm)
{
    __shared__ float redbuf[4];

    const int tid = threadIdx.x;
    const int bc  = blockIdx.x * 256 + tid;   // block-channel [0, NBC)
    const int wb  = bc & 63;                  // = lane -> coalesced columns
    const int hb  = (bc >> 6) & 63;
    const int img = bc >> 12;                 // b*3 + c in [0,48)
    const int base = (img * 512 + hb * 8) * 512 + wb * 8;

    float X[8][8], Y[8][8];
#pragma unroll
    for (int i = 0; i < 8; i++) {
        const float4 a0 = *reinterpret_cast<const float4*>(x + base + i * 512);
        const float4 a1 = *reinterpret_cast<const float4*>(x + base + i * 512 + 4);
        X[i][0]=a0.x; X[i][1]=a0.y; X[i][2]=a0.z; X[i][3]=a0.w;
        X[i][4]=a1.x; X[i][5]=a1.y; X[i][6]=a1.z; X[i][7]=a1.w;
        const float4 b0 = *reinterpret_cast<const float4*>(y + base + i * 512);
        const float4 b1 = *reinterpret_cast<const float4*>(y + base + i * 512 + 4);
        Y[i][0]=b0.x; Y[i][1]=b0.y; Y[i][2]=b0.z; Y[i][3]=b0.w;
        Y[i][4]=b1.x; Y[i][5]=b1.y; Y[i][6]=b1.z; Y[i][7]=b1.w;
    }

    float acc = 0.f;
#pragma unroll 1                     // keep code small; only w depends on j
    for (int j = 0; j < 8; j++) {
        float wj[8];
#pragma unroll
        for (int c = 0; c < 8; c++) wj[c] = Wm.w[j * 8 + c];   // uniform s_loads

        float ux[8], uy[8], uxx[8], uyy[8], uxy[8];
#pragma unroll
        for (int i = 0; i < 8; i++) {
            float sx = 0.f, sy = 0.f, sxx = 0.f, syy = 0.f, sxy = 0.f;
#pragma unroll
            for (int c = 0; c < 8; c++) {
                const float xv = X[i][c], yv = Y[i][c];
                const float xw = xv * wj[c];
                const float yw = yv * wj[c];
                sx += xw;  sy += yw;
                sxx = fmaf(xw, xv, sxx);
                syy = fmaf(yw, yv, syy);
                sxy = fmaf(xw, yv, sxy);
            }
            ux[i] = sx; uy[i] = sy; uxx[i] = sxx; uyy[i] = syy; uxy[i] = sxy;
        }

#pragma unroll
        for (int i = 0; i < 8; i++) {
            float mx = 0.f, my = 0.f, mxx = 0.f, myy = 0.f, mxy = 0.f;
#pragma unroll
            for (int k = 0; k < 8; k++) {
                const float wv = Wm.w[i * 8 + k];   // compile-time index
                mx  = fmaf(wv, ux[k],  mx);
                my  = fmaf(wv, uy[k],  my);
                mxx = fmaf(wv, uxx[k], mxx);
                myy = fmaf(wv, uyy[k], myy);
                mxy = fmaf(wv, uxy[k], mxy);
            }
            const float sigx  = mxx - mx * mx;
            const float sigy  = myy - my * my;
            const float sigxy = mxy - mx * my;
            const float num = fmaf(2.f, mx * my, C1) * fmaf(2.f, sigxy, C2);
            const float den = (fmaf(mx, mx, my * my) + C1) * (sigx + sigy + C2);
            float r = __builtin_amdgcn_rcpf(den);
            r = r * (2.f - den * r);               // Newton -> full fp32
            acc = fmaf(num, r, acc);
        }
    }

    // 64-lane butterfly, 4 wave partials via LDS, one atomic per block
#pragma unroll
    for (int off = 32; off > 0; off >>= 1) acc += __shfl_xor(acc, off, 64);
    if ((tid & 63) == 0) redbuf[tid >> 6] = acc;
    __syncthreads();
    if (tid == 0) {
        const float bs = (redbuf[0] + redbuf[1]) + (redbuf[2] + redbuf[3]);
        const long long fx = llrintf(bs * FIXSCALE);
        atomicAdd(&slots[blockIdx.x & (NSLOT - 1)], (unsigned long long)fx);
        __threadfence();
        const unsigned old = atomicAdd(counter, 1u);
        if (old == (unsigned)(GRID - 1)) {
            __threadfence();
            long long tot = 0;
#pragma unroll
            for (int i = 0; i < NSLOT; i++)
                tot += (long long)atomicAdd(&slots[i], 0ull);   // coherent read
            out[0] = (float)(1.0 - ((double)tot / (double)FIXSCALE) / NPIX);
        }
    }
}

static WMat make_w() {
    double g[11]; double s = 0.0;
    for (int k = 0; k < 11; k++) { double d = k - 5.0; g[k] = exp(-d * d / 4.5); s += g[k]; }
    for (int k = 0; k < 11; k++) g[k] /= s;
    WMat W{};
    for (int j = 0; j < 8; j++)
        for (int k = 0; k < 11; k++) {
            int t = j + k - 5;
            int rr = t < 0 ? -t : (t > 7 ? 14 - t : t);
            W.w[j * 8 + rr] += (float)g[k];
        }
    return W;
}

extern "C" void kernel_launch(void* const* d_in, const int* in_sizes, int n_in,
                              void* d_out, int out_size, void* d_ws, size_t ws_size,
                              hipStream_t stream) {
    const float* x = (const float*)d_in[0];
    const float* y = (const float*)d_in[1];
    unsigned long long* slots = (unsigned long long*)d_ws;        // 16 x u64
    unsigned* counter = (unsigned*)((char*)d_ws + NSLOT * 8);     // u32
    WMat W = make_w();
    hipMemsetAsync(d_ws, 0, NSLOT * 8 + 4, stream);               // capture-safe
    ssim_fused<<<GRID, 256, 0, stream>>>(x, y, slots, counter, (float*)d_out, W);
}

// Round 10
// 155.795 us; speedup vs baseline: 2.3241x; 1.0228x over previous
//
#include <hip/hip_runtime.h>
#include <math.h>

// SSIM loss on 8x8 blockified images (16,3,512,512) fp32.
// v5 = v4 structure (one thread per block-channel, all-VGPR, no cross-lane /
// LDS / barriers in compute) + v_pk_fma_f32 packing + 256-VGPR budget.
// v4 post-mortem: spill eliminated (WRITE 12.3MB->48KB) but time identical
// 70us, VALUBusy 44% -> limiter is VALU ISSUE, not memory. 3 waves/SIMD at
// 1 inst/14cyc per wave = dependency-stall-bound at the 128-reg tier.
// v5 attacks: (a) pack all conv loops into float2 (v_pk_fma_f32) -> ~0.6x
// inst count; (b) amdgpu_waves_per_eu(2) (min-only) -> up to 256 VGPR so
// the ~200-reg live set gets real registers and the 40 independent
// accumulator chains can interleave (ILP), at 2 waves/SIMD.
// Math: reflect-pad + 11x11 separable Gaussian on 8x8 block == W*S*W^T, W =
// fold matrix. Stage1 per output col j: pair-dots of rows with w_j (packed,
// horizontal add deferred to scalar u). Stage2 per output row i: packed
// k-pair dots. SSIM epilogue scalar. Reduction: 64-lane shuffle -> 4 wave
// partials -> fixed-point 2^30 int64 atomicAdd into 16 slots; last block
// (device counter) writes 1-mean.

#define NBC      196608      // 16*3*64*64 block-channels
#define NPIX     12582912.0  // total ssim_map elements
#define GRID     768         // NBC / 256 threads
#define NSLOT    16
#define FIXSCALE 1073741824.0f // 2^30
#define C1       1.0e-4f
#define C2       9.0e-4f

typedef float v2f __attribute__((ext_vector_type(2)));

struct WMat { float w[64]; };

__global__ __launch_bounds__(256)
__attribute__((amdgpu_waves_per_eu(2)))
void ssim_fused(
    const float* __restrict__ x, const float* __restrict__ y,
    unsigned long long* __restrict__ slots, unsigned* __restrict__ counter,
    float* __restrict__ out, WMat Wm)
{
    __shared__ float redbuf[4];

    const int tid = threadIdx.x;
    const int bc  = blockIdx.x * 256 + tid;   // block-channel [0, NBC)
    const int wb  = bc & 63;                  // = lane -> coalesced columns
    const int hb  = (bc >> 6) & 63;
    const int img = bc >> 12;                 // b*3 + c in [0,48)
    const int base = (img * 512 + hb * 8) * 512 + wb * 8;

    v2f X2[8][4], Y2[8][4];                   // pair-packed rows
#pragma unroll
    for (int i = 0; i < 8; i++) {
        const float4 a0 = *reinterpret_cast<const float4*>(x + base + i * 512);
        const float4 a1 = *reinterpret_cast<const float4*>(x + base + i * 512 + 4);
        X2[i][0] = (v2f){a0.x, a0.y}; X2[i][1] = (v2f){a0.z, a0.w};
        X2[i][2] = (v2f){a1.x, a1.y}; X2[i][3] = (v2f){a1.z, a1.w};
        const float4 b0 = *reinterpret_cast<const float4*>(y + base + i * 512);
        const float4 b1 = *reinterpret_cast<const float4*>(y + base + i * 512 + 4);
        Y2[i][0] = (v2f){b0.x, b0.y}; Y2[i][1] = (v2f){b0.z, b0.w};
        Y2[i][2] = (v2f){b1.x, b1.y}; Y2[i][3] = (v2f){b1.z, b1.w};
    }

    float acc = 0.f;
#pragma unroll 1                     // keep code I-cache-resident
    for (int j = 0; j < 8; j++) {
        v2f wj2[4];
#pragma unroll
        for (int c2 = 0; c2 < 4; c2++)
            wj2[c2] = (v2f){Wm.w[j * 8 + 2 * c2], Wm.w[j * 8 + 2 * c2 + 1]};

        float ux[8], uy[8], uxx[8], uyy[8], uxy[8];
#pragma unroll
        for (int i = 0; i < 8; i++) {
            v2f sx = {0.f, 0.f}, sy = {0.f, 0.f};
            v2f sxx = {0.f, 0.f}, syy = {0.f, 0.f}, sxy = {0.f, 0.f};
#pragma unroll
            for (int c2 = 0; c2 < 4; c2++) {
                const v2f xv = X2[i][c2], yv = Y2[i][c2];
                const v2f xw = xv * wj2[c2];        // v_pk_mul_f32
                const v2f yw = yv * wj2[c2];
                sx += xw;  sy += yw;                // v_pk_add_f32
                sxx = __builtin_elementwise_fma(xw, xv, sxx);  // v_pk_fma_f32
                syy = __builtin_elementwise_fma(yw, yv, syy);
                sxy = __builtin_elementwise_fma(xw, yv, sxy);
            }
            ux[i]  = sx.x + sx.y;   uy[i]  = sy.x + sy.y;
            uxx[i] = sxx.x + sxx.y; uyy[i] = syy.x + syy.y;
            uxy[i] = sxy.x + sxy.y;
        }

#pragma unroll
        for (int i = 0; i < 8; i++) {
            v2f am = {0.f, 0.f}, bm = {0.f, 0.f};
            v2f axx = {0.f, 0.f}, ayy = {0.f, 0.f}, axy = {0.f, 0.f};
#pragma unroll
            for (int k2 = 0; k2 < 4; k2++) {
                const v2f wv = (v2f){Wm.w[i * 8 + 2 * k2], Wm.w[i * 8 + 2 * k2 + 1]};
                const v2f u0 = (v2f){ux[2 * k2],  ux[2 * k2 + 1]};
                const v2f u1 = (v2f){uy[2 * k2],  uy[2 * k2 + 1]};
                const v2f u2 = (v2f){uxx[2 * k2], uxx[2 * k2 + 1]};
                const v2f u3 = (v2f){uyy[2 * k2], uyy[2 * k2 + 1]};
                const v2f u4 = (v2f){uxy[2 * k2], uxy[2 * k2 + 1]};
                am  = __builtin_elementwise_fma(wv, u0, am);
                bm  = __builtin_elementwise_fma(wv, u1, bm);
                axx = __builtin_elementwise_fma(wv, u2, axx);
                ayy = __builtin_elementwise_fma(wv, u3, ayy);
                axy = __builtin_elementwise_fma(wv, u4, axy);
            }
            const float mx  = am.x + am.y,   my  = bm.x + bm.y;
            const float mxx = axx.x + axx.y, myy = ayy.x + ayy.y;
            const float mxy = axy.x + axy.y;

            const float sigx  = mxx - mx * mx;
            const float sigy  = myy - my * my;
            const float sigxy = mxy - mx * my;
            const float num = fmaf(2.f, mx * my, C1) * fmaf(2.f, sigxy, C2);
            const float den = (fmaf(mx, mx, my * my) + C1) * (sigx + sigy + C2);
            float r = __builtin_amdgcn_rcpf(den);
            r = r * (2.f - den * r);               // Newton -> full fp32
            acc = fmaf(num, r, acc);
        }
    }

    // 64-lane butterfly, 4 wave partials via LDS, one atomic per block
#pragma unroll
    for (int off = 32; off > 0; off >>= 1) acc += __shfl_xor(acc, off, 64);
    if ((tid & 63) == 0) redbuf[tid >> 6] = acc;
    __syncthreads();
    if (tid == 0) {
        const float bs = (redbuf[0] + redbuf[1]) + (redbuf[2] + redbuf[3]);
        const long long fx = llrintf(bs * FIXSCALE);
        atomicAdd(&slots[blockIdx.x & (NSLOT - 1)], (unsigned long long)fx);
        __threadfence();
        const unsigned old = atomicAdd(counter, 1u);
        if (old == (unsigned)(GRID - 1)) {
            __threadfence();
            long long tot = 0;
#pragma unroll
            for (int i = 0; i < NSLOT; i++)
                tot += (long long)atomicAdd(&slots[i], 0ull);   // coherent read
            out[0] = (float)(1.0 - ((double)tot / (double)FIXSCALE) / NPIX);
        }
    }
}

static WMat make_w() {
    double g[11]; double s = 0.0;
    for (int k = 0; k < 11; k++) { double d = k - 5.0; g[k] = exp(-d * d / 4.5); s += g[k]; }
    for (int k = 0; k < 11; k++) g[k] /= s;
    WMat W{};
    for (int j = 0; j < 8; j++)
        for (int k = 0; k < 11; k++) {
            int t = j + k - 5;
            int rr = t < 0 ? -t : (t > 7 ? 14 - t : t);
            W.w[j * 8 + rr] += (float)g[k];
        }
    return W;
}

extern "C" void kernel_launch(void* const* d_in, const int* in_sizes, int n_in,
                              void* d_out, int out_size, void* d_ws, size_t ws_size,
                              hipStream_t stream) {
    const float* x = (const float*)d_in[0];
    const float* y = (const float*)d_in[1];
    unsigned long long* slots = (unsigned long long*)d_ws;        // 16 x u64
    unsigned* counter = (unsigned*)((char*)d_ws + NSLOT * 8);     // u32
    WMat W = make_w();
    hipMemsetAsync(d_ws, 0, NSLOT * 8 + 4, stream);               // capture-safe
    ssim_fused<<<GRID, 256, 0, stream>>>(x, y, slots, counter, (float*)d_out, W);
}

// Round 11
// 155.346 us; speedup vs baseline: 2.3309x; 1.0029x over previous
//
#include <hip/hip_runtime.h>
#include <math.h>

// SSIM loss on 8x8 blockified images (16,3,512,512) fp32.
// v6 = v5 structure (one thread per block-channel, all-VGPR, packed fp32,
// no cross-lane/LDS/barriers in compute) + COMPILE-TIME W table.
// v5 post-mortem: cutting VALU inst count (v4->v5) left time invariant and
// VALUBusy fell 44->37% -> non-VALU serializer. Diagnosis: W lived in
// kernarg memory; stage 2 reads all 64 weights per j-iteration and the
// compiler (96-112 SGPRs) re-s_loads them each iter -> lgkmcnt chains gate
// the FMAs. Fix: constexpr W -> stage-2 weights are literals, materialized
// by s_mov (SALU pipe, no memory, no waits, remat-free). Stage 1 keeps one
// 32B .rodata scalar load per j-iter (amortized over ~600 inst).
// Math: reflect-pad + 11x11 separable Gaussian on 8x8 block == W*S*W^T, W =
// reflect-folded fold matrix; stage1 per output col j (packed pair-dots over
// row cols), stage2 per output row i (packed k-pair dots), SSIM epilogue.
// Reduction: 64-lane shuffle -> 4 wave partials -> fixed-point 2^30 int64
// atomicAdd into 16 slots; last block (device counter) writes 1-mean.

#define NBC      196608      // 16*3*64*64 block-channels
#define NPIX     12582912.0  // total ssim_map elements
#define GRID     768         // NBC / 256 threads
#define NSLOT    16
#define FIXSCALE 1073741824.0f // 2^30
#define C1       1.0e-4f
#define C2       9.0e-4f

typedef float v2f __attribute__((ext_vector_type(2)));

struct WTab { float w[64]; };

// constexpr exp for x<=0: e^x = (e^(x/64))^64, 20-term Taylor -> double-exact
constexpr double cexp_(double x) {
    double t = x / 64.0;
    double s = 1.0, term = 1.0;
    for (int n = 1; n < 20; n++) { term = term * t / n; s += term; }
    for (int i = 0; i < 6; i++) s = s * s;
    return s;
}

constexpr WTab build_w() {
    double g[11] = {};
    double z = 0.0;
    for (int k = 0; k < 11; k++) { double d = k - 5.0; g[k] = cexp_(-d * d / 4.5); z += g[k]; }
    double acc[64] = {};
    for (int j = 0; j < 8; j++)
        for (int k = 0; k < 11; k++) {
            int t = j + k - 5;
            int rr = t < 0 ? -t : (t > 7 ? 14 - t : t);
            acc[j * 8 + rr] += g[k] / z;
        }
    WTab W{};
    for (int i = 0; i < 64; i++) W.w[i] = (float)acc[i];
    return W;
}

constexpr WTab WT = build_w();   // usable from device; compile-time folds

__global__ __launch_bounds__(256)
__attribute__((amdgpu_waves_per_eu(2)))
void ssim_fused(
    const float* __restrict__ x, const float* __restrict__ y,
    unsigned long long* __restrict__ slots, unsigned* __restrict__ counter,
    float* __restrict__ out)
{
    __shared__ float redbuf[4];

    const int tid = threadIdx.x;
    const int bc  = blockIdx.x * 256 + tid;   // block-channel [0, NBC)
    const int wb  = bc & 63;                  // = lane -> coalesced columns
    const int hb  = (bc >> 6) & 63;
    const int img = bc >> 12;                 // b*3 + c in [0,48)
    const int base = (img * 512 + hb * 8) * 512 + wb * 8;

    v2f X2[8][4], Y2[8][4];                   // pair-packed rows
#pragma unroll
    for (int i = 0; i < 8; i++) {
        const float4 a0 = *reinterpret_cast<const float4*>(x + base + i * 512);
        const float4 a1 = *reinterpret_cast<const float4*>(x + base + i * 512 + 4);
        X2[i][0] = (v2f){a0.x, a0.y}; X2[i][1] = (v2f){a0.z, a0.w};
        X2[i][2] = (v2f){a1.x, a1.y}; X2[i][3] = (v2f){a1.z, a1.w};
        const float4 b0 = *reinterpret_cast<const float4*>(y + base + i * 512);
        const float4 b1 = *reinterpret_cast<const float4*>(y + base + i * 512 + 4);
        Y2[i][0] = (v2f){b0.x, b0.y}; Y2[i][1] = (v2f){b0.z, b0.w};
        Y2[i][2] = (v2f){b1.x, b1.y}; Y2[i][3] = (v2f){b1.z, b1.w};
    }

    float acc = 0.f;
#pragma unroll 1                     // keep code I-cache-resident
    for (int j = 0; j < 8; j++) {
        v2f wj2[4];                  // runtime j: one 32B .rodata scalar load
#pragma unroll
        for (int c2 = 0; c2 < 4; c2++)
            wj2[c2] = (v2f){WT.w[j * 8 + 2 * c2], WT.w[j * 8 + 2 * c2 + 1]};

        float ux[8], uy[8], uxx[8], uyy[8], uxy[8];
#pragma unroll
        for (int i = 0; i < 8; i++) {
            v2f sx = {0.f, 0.f}, sy = {0.f, 0.f};
            v2f sxx = {0.f, 0.f}, syy = {0.f, 0.f}, sxy = {0.f, 0.f};
#pragma unroll
            for (int c2 = 0; c2 < 4; c2++) {
                const v2f xv = X2[i][c2], yv = Y2[i][c2];
                const v2f xw = xv * wj2[c2];        // v_pk_mul_f32
                const v2f yw = yv * wj2[c2];
                sx += xw;  sy += yw;                // v_pk_add_f32
                sxx = __builtin_elementwise_fma(xw, xv, sxx);  // v_pk_fma_f32
                syy = __builtin_elementwise_fma(yw, yv, syy);
                sxy = __builtin_elementwise_fma(xw, yv, sxy);
            }
            ux[i]  = sx.x + sx.y;   uy[i]  = sy.x + sy.y;
            uxx[i] = sxx.x + sxx.y; uyy[i] = syy.x + syy.y;
            uxy[i] = sxy.x + sxy.y;
        }

#pragma unroll
        for (int i = 0; i < 8; i++) {
            v2f am = {0.f, 0.f}, bm = {0.f, 0.f};
            v2f axx = {0.f, 0.f}, ayy = {0.f, 0.f}, axy = {0.f, 0.f};
#pragma unroll
            for (int k2 = 0; k2 < 4; k2++) {
                // compile-time indices -> literal pair, s_mov-materialized
                const v2f wv = (v2f){WT.w[i * 8 + 2 * k2], WT.w[i * 8 + 2 * k2 + 1]};
                const v2f u0 = (v2f){ux[2 * k2],  ux[2 * k2 + 1]};
                const v2f u1 = (v2f){uy[2 * k2],  uy[2 * k2 + 1]};
                const v2f u2 = (v2f){uxx[2 * k2], uxx[2 * k2 + 1]};
                const v2f u3 = (v2f){uyy[2 * k2], uyy[2 * k2 + 1]};
                const v2f u4 = (v2f){uxy[2 * k2], uxy[2 * k2 + 1]};
                am  = __builtin_elementwise_fma(wv, u0, am);
                bm  = __builtin_elementwise_fma(wv, u1, bm);
                axx = __builtin_elementwise_fma(wv, u2, axx);
                ayy = __builtin_elementwise_fma(wv, u3, ayy);
                axy = __builtin_elementwise_fma(wv, u4, axy);
            }
            const float mx  = am.x + am.y,   my  = bm.x + bm.y;
            const float mxx = axx.x + axx.y, myy = ayy.x + ayy.y;
            const float mxy = axy.x + axy.y;

            const float sigx  = mxx - mx * mx;
            const float sigy  = myy - my * my;
            const float sigxy = mxy - mx * my;
            const float num = fmaf(2.f, mx * my, C1) * fmaf(2.f, sigxy, C2);
            const float den = (fmaf(mx, mx, my * my) + C1) * (sigx + sigy + C2);
            float r = __builtin_amdgcn_rcpf(den);
            r = r * (2.f - den * r);               // Newton -> full fp32
            acc = fmaf(num, r, acc);
        }
    }

    // 64-lane butterfly, 4 wave partials via LDS, one atomic per block
#pragma unroll
    for (int off = 32; off > 0; off >>= 1) acc += __shfl_xor(acc, off, 64);
    if ((tid & 63) == 0) redbuf[tid >> 6] = acc;
    __syncthreads();
    if (tid == 0) {
        const float bs = (redbuf[0] + redbuf[1]) + (redbuf[2] + redbuf[3]);
        const long long fx = llrintf(bs * FIXSCALE);
        atomicAdd(&slots[blockIdx.x & (NSLOT - 1)], (unsigned long long)fx);
        __threadfence();
        const unsigned old = atomicAdd(counter, 1u);
        if (old == (unsigned)(GRID - 1)) {
            __threadfence();
            long long tot = 0;
#pragma unroll
            for (int i = 0; i < NSLOT; i++)
                tot += (long long)atomicAdd(&slots[i], 0ull);   // coherent read
            out[0] = (float)(1.0 - ((double)tot / (double)FIXSCALE) / NPIX);
        }
    }
}

extern "C" void kernel_launch(void* const* d_in, const int* in_sizes, int n_in,
                              void* d_out, int out_size, void* d_ws, size_t ws_size,
                              hipStream_t stream) {
    const float* x = (const float*)d_in[0];
    const float* y = (const float*)d_in[1];
    unsigned long long* slots = (unsigned long long*)d_ws;        // 16 x u64
    unsigned* counter = (unsigned*)((char*)d_ws + NSLOT * 8);     // u32
    hipMemsetAsync(d_ws, 0, NSLOT * 8 + 4, stream);               // capture-safe
    ssim_fused<<<GRID, 256, 0, stream>>>(x, y, slots, counter, (float*)d_out);
}